// Round 2
// baseline (307.072 us; speedup 1.0000x reference)
//
#include <hip/hip_runtime.h>
#include <hip/hip_bf16.h>

#define NN 20000
#define NE 320000
#define FDIM 32
#define YS 544      // 16 conv basis blocks * 32 + 32 fc cols

typedef __attribute__((ext_vector_type(8))) short short8;
typedef __attribute__((ext_vector_type(4))) float f32x4;
typedef __attribute__((ext_vector_type(4))) _Float16 half4;

__device__ __forceinline__ unsigned short f2bf(float v) {
    unsigned u = __float_as_uint(v);
    unsigned r = (u + 0x7fffu + ((u >> 16) & 1u)) >> 16;
    return (unsigned short)r;
}
__device__ __forceinline__ float bf2f(unsigned short s) {
    return __uint_as_float(((unsigned)s) << 16);
}

struct WPtrs { const float* cw[4]; const float* fw[4]; };

// ---- build combined weight matrices (all 4 layers, one launch)
__global__ __launch_bounds__(256) void prepw_kernel(WPtrs wp, unsigned short* __restrict__ out) {
    int idx = blockIdx.x * 256 + threadIdx.x;       // 4 * 32*544 = 69632
    if (idx >= 4 * 32 * YS) return;
    int l = idx / (32 * YS);
    int r = idx - l * 32 * YS;
    int k = r / YS, c = r - k * YS;
    float v = (c < 512) ? wp.cw[l][((c >> 5) * 32 + k) * 32 + (c & 31)]
                        : wp.fw[l][k * 32 + (c & 31)];
    out[idx] = f2bf(v);
}

// ---- CSR build: histogram
__global__ __launch_bounds__(256) void hist_kernel(const int* __restrict__ ei, int* __restrict__ counts) {
    int e = blockIdx.x * 256 + threadIdx.x;
    if (e < NE) atomicAdd(&counts[ei[e]], 1);
}

// ---- CSR build: single-block scan, 20 elements/thread, fully unrolled
__global__ __launch_bounds__(1024) void scan_kernel(const int* __restrict__ counts,
                                                    int* __restrict__ rowst,
                                                    int* __restrict__ cursor) {
    __shared__ int s[1024];
    int t = threadIdx.x;
    int base = t * 20;                    // 1024*20 = 20480 >= 20000
    int v[20];
    int sum = 0;
#pragma unroll
    for (int i = 0; i < 20; i++) {
        int idx = base + i;
        v[i] = (idx < NN) ? counts[idx] : 0;
        sum += v[i];
    }
    s[t] = sum;
    __syncthreads();
#pragma unroll
    for (int off = 1; off < 1024; off <<= 1) {
        int add = (t >= off) ? s[t - off] : 0;
        __syncthreads();
        s[t] += add;
        __syncthreads();
    }
    int run = s[t] - sum;                 // exclusive across threads
    if (t == 0) rowst[0] = 0;
#pragma unroll
    for (int i = 0; i < 20; i++) {
        int idx = base + i;
        if (idx < NN) {
            cursor[idx] = run;
            rowst[idx + 1] = run + v[i];
        }
        run += v[i];
    }
}

// ---- CSR fill + edge basis precompute (phi is layer-invariant)
__global__ __launch_bounds__(256) void fill_kernel(const int* __restrict__ ei,
                                                   const int* __restrict__ ej,
                                                   const float* __restrict__ attr,
                                                   int* __restrict__ cursor,
                                                   int* __restrict__ meta,
                                                   half4* __restrict__ wph) {
    int e = blockIdx.x * 256 + threadIdx.x;
    if (e >= NE) return;
    int i = ei[e], j = ej[e];
    int p = atomicAdd(&cursor[i], 1);
    float2 a = ((const float2*)attr)[e];
    float d0 = fminf(fmaxf(a.x, -1.f), 1.f);
    float d1 = fminf(fmaxf(a.y, -1.f), 1.f);
    float tx = (d0 + 1.f) * 1.5f;
    float ty = (d1 + 1.f) * 1.5f;
    int ix = min(2, max(0, (int)floorf(tx)));
    int iy = min(2, max(0, (int)floorf(ty)));
    float ux = tx - (float)ix;
    float uy = ty - (float)iy;
    float m = (i != j) ? 1.f : 0.f;   // centerIgnore
    half4 w;
    w[0] = (_Float16)((1.f - ux) * (1.f - uy) * m);   // (dx=0,dy=0)
    w[1] = (_Float16)((1.f - ux) * uy * m);           // (dx=0,dy=1)
    w[2] = (_Float16)(ux * (1.f - uy) * m);           // (dx=1,dy=0)
    w[3] = (_Float16)(ux * uy * m);                   // (dx=1,dy=1)
    meta[p] = j | ((ix * 4 + iy) << 16);
    wph[p] = w;
}

// ---- y[n][544] = bf16( (relu?)A[n][0..31] @ Wext ), one MFMA per 16x16 tile (K=32)
__global__ __launch_bounds__(256) void gemm_kernel(const float* __restrict__ A,
                                                   const unsigned short* __restrict__ Wl,
                                                   unsigned short* __restrict__ y,
                                                   int relu) {
    int wv = threadIdx.x >> 6, lane = threadIdx.x & 63;
    int ct = blockIdx.y * 4 + wv;
    if (ct >= 34) return;                 // 544/16 = 34 col tiles
    int c0 = ct * 16;
    int m0 = blockIdx.x * 16;             // 20000/16 = 1250 exact
    int row = lane & 15;
    int kb = (lane >> 4) * 8;
    const float* ar = A + (size_t)(m0 + row) * 32 + kb;
    short8 av, bv;
#pragma unroll
    for (int i = 0; i < 8; i++) {
        float v = ar[i];
        if (relu) v = fmaxf(v, 0.f);
        av[i] = (short)f2bf(v);
    }
    int col = c0 + (lane & 15);
#pragma unroll
    for (int i = 0; i < 8; i++)
        bv[i] = (short)Wl[(size_t)(kb + i) * YS + col];
    f32x4 acc = {0.f, 0.f, 0.f, 0.f};
    acc = __builtin_amdgcn_mfma_f32_16x16x32_bf16(av, bv, acc, 0, 0, 0);
#pragma unroll
    for (int r = 0; r < 4; r++) {
        int orow = m0 + (lane >> 4) * 4 + r;   // C/D: col=lane&15, row=(lane>>4)*4+r
        y[(size_t)orow * YS + col] = f2bf(acc[r]);
    }
}

// ---- per-node accumulation: one wave per node, lane=(dy, fout)
// mode: 0 = first layer (no residual), 1 = mid (residual), 2 = last (residual + scale -> d_out)
__global__ __launch_bounds__(256) void node_kernel(const unsigned short* __restrict__ y,
                                                   const half4* __restrict__ wph,
                                                   const int* __restrict__ meta,
                                                   const int* __restrict__ rowst,
                                                   const float* __restrict__ bias,
                                                   const float* __restrict__ ansin,
                                                   float* __restrict__ ansout,
                                                   int mode) {
    int node = blockIdx.x * 4 + (threadIdx.x >> 6);
    int lane = threadIdx.x & 63;
    int f = lane & 31;
    int dy = lane >> 5;
    int r0 = rowst[node], r1 = rowst[node + 1];
    float acc = 0.f;
    for (int q = r0; q < r1; ++q) {
        int pk = meta[q];
        half4 w4 = wph[q];
        int jc = pk & 0xFFFF;
        int bbc = pk >> 16;
        const unsigned short* yr = y + (size_t)jc * YS + (bbc + dy) * 32 + f;
        float v0 = bf2f(yr[0]);     // block (bx0,   by0+dy)
        float v1 = bf2f(yr[128]);   // block (bx0+1, by0+dy)
        float wa = dy ? (float)w4[1] : (float)w4[0];
        float wb = dy ? (float)w4[3] : (float)w4[2];
        acc += wa * v0;
        acc += wb * v1;
    }
    acc += __shfl_xor(acc, 32);     // combine the two dy halves
    if (lane < 32) {
        float val = acc + bf2f(y[(size_t)node * YS + 512 + f]) + bias[f];
        if (mode) val += ansin[(size_t)node * 32 + f];
        if (mode == 2) val *= (1.f / 128.f);
        ansout[(size_t)node * 32 + f] = val;
    }
}

extern "C" void kernel_launch(void* const* d_in, const int* in_sizes, int n_in,
                              void* d_out, int out_size, void* d_ws, size_t ws_size,
                              hipStream_t stream) {
    const float* feat = (const float*)d_in[0];
    const int* ei = (const int*)d_in[1];
    const int* ej = (const int*)d_in[2];
    const float* attr = (const float*)d_in[3];
    WPtrs wp;
    const float* fcB[4];
    if (n_in >= 16) {
        for (int l = 0; l < 4; l++) {
            wp.cw[l] = (const float*)d_in[4 + l];
            wp.fw[l] = (const float*)d_in[8 + l];
            fcB[l]   = (const float*)d_in[12 + l];
        }
    } else {
        const float* cb = (const float*)d_in[4];
        const float* fb = (const float*)d_in[5];
        const float* bb = (const float*)d_in[6];
        for (int l = 0; l < 4; l++) {
            wp.cw[l] = cb + (size_t)l * 16 * 32 * 32;
            wp.fw[l] = fb + (size_t)l * 32 * 32;
            fcB[l]   = bb + (size_t)l * 32;
        }
    }

    // workspace bump allocator (256B aligned)
    char* p = (char*)d_ws;
    auto alloc = [&](size_t bytes) -> void* {
        void* r = (void*)p;
        p += (bytes + 255) & ~(size_t)255;
        return r;
    };
    unsigned short* wext = (unsigned short*)alloc(4 * 32 * YS * sizeof(unsigned short));
    half4* wph    = (half4*)alloc((size_t)NE * sizeof(half4));
    int* meta     = (int*)alloc((size_t)NE * sizeof(int));
    int* counts   = (int*)alloc((size_t)NN * sizeof(int));
    int* cursor   = (int*)alloc((size_t)NN * sizeof(int));
    int* rowst    = (int*)alloc((size_t)(NN + 1) * sizeof(int));
    unsigned short* y = (unsigned short*)alloc((size_t)NN * YS * sizeof(unsigned short));
    float* ans    = (float*)alloc((size_t)NN * FDIM * sizeof(float));
    float* outf   = (float*)d_out;

    hipMemsetAsync(counts, 0, (size_t)NN * sizeof(int), stream);

    prepw_kernel<<<(4 * 32 * YS + 255) / 256, 256, 0, stream>>>(wp, wext);
    hist_kernel<<<(NE + 255) / 256, 256, 0, stream>>>(ei, counts);
    scan_kernel<<<1, 1024, 0, stream>>>(counts, rowst, cursor);
    fill_kernel<<<(NE + 255) / 256, 256, 0, stream>>>(ei, ej, attr, cursor, meta, wph);

    for (int l = 0; l < 4; l++) {
        const float* A = (l == 0) ? feat : ans;
        gemm_kernel<<<dim3(NN / 16, 9), 256, 0, stream>>>(A, wext + (size_t)l * 32 * YS, y, l > 0);
        int mode = (l == 0) ? 0 : ((l == 3) ? 2 : 1);
        float* dst = (l == 3) ? outf : ans;
        node_kernel<<<NN / 4, 256, 0, stream>>>(y, wph, meta, rowst, fcB[l],
                                                ans, dst, mode);
    }
}

// Round 3
// 226.766 us; speedup vs baseline: 1.3541x; 1.3541x over previous
//
#include <hip/hip_runtime.h>
#include <hip/hip_bf16.h>

#define NN 20000
#define NE 320000
#define FDIM 32
#define YS 544      // 16 conv basis blocks * 32 + 32 fc cols

typedef __attribute__((ext_vector_type(8))) short short8;
typedef __attribute__((ext_vector_type(4))) float f32x4;

__device__ __forceinline__ unsigned short f2bf(float v) {
    unsigned u = __float_as_uint(v);
    unsigned r = (u + 0x7fffu + ((u >> 16) & 1u)) >> 16;
    return (unsigned short)r;
}
__device__ __forceinline__ float bf2f(unsigned short s) {
    return __uint_as_float(((unsigned)s) << 16);
}
__device__ __forceinline__ unsigned short f2h(float v) {
    union { _Float16 h; unsigned short u; } cv;
    cv.h = (_Float16)v;
    return cv.u;
}
__device__ __forceinline__ float h2f(unsigned short u) {
    union { unsigned short u; _Float16 h; } cv;
    cv.u = u;
    return (float)cv.h;
}

struct WPtrs { const float* cw[4]; const float* fw[4]; };

// ---- build combined weight matrices (all 4 layers, one launch)
__global__ __launch_bounds__(256) void prepw_kernel(WPtrs wp, unsigned short* __restrict__ out) {
    int idx = blockIdx.x * 256 + threadIdx.x;       // 4 * 32*544 = 69632
    if (idx >= 4 * 32 * YS) return;
    int l = idx / (32 * YS);
    int r = idx - l * 32 * YS;
    int k = r / YS, c = r - k * YS;
    float v = (c < 512) ? wp.cw[l][((c >> 5) * 32 + k) * 32 + (c & 31)]
                        : wp.fw[l][k * 32 + (c & 31)];
    out[idx] = f2bf(v);
}

// ---- CSR build: histogram
__global__ __launch_bounds__(256) void hist_kernel(const int* __restrict__ ei, int* __restrict__ counts) {
    int e = blockIdx.x * 256 + threadIdx.x;
    if (e < NE) atomicAdd(&counts[ei[e]], 1);
}

// ---- CSR build: single-block scan, 20 elements/thread, fully unrolled
__global__ __launch_bounds__(1024) void scan_kernel(const int* __restrict__ counts,
                                                    int* __restrict__ rowst,
                                                    int* __restrict__ cursor) {
    __shared__ int s[1024];
    int t = threadIdx.x;
    int base = t * 20;                    // 1024*20 = 20480 >= 20000
    int v[20];
    int sum = 0;
#pragma unroll
    for (int i = 0; i < 20; i++) {
        int idx = base + i;
        v[i] = (idx < NN) ? counts[idx] : 0;
        sum += v[i];
    }
    s[t] = sum;
    __syncthreads();
#pragma unroll
    for (int off = 1; off < 1024; off <<= 1) {
        int add = (t >= off) ? s[t - off] : 0;
        __syncthreads();
        s[t] += add;
        __syncthreads();
    }
    int run = s[t] - sum;                 // exclusive across threads
    if (t == 0) rowst[0] = 0;
#pragma unroll
    for (int i = 0; i < 20; i++) {
        int idx = base + i;
        if (idx < NN) {
            cursor[idx] = run;
            rowst[idx + 1] = run + v[i];
        }
        run += v[i];
    }
}

// ---- CSR fill + edge basis precompute (phi is layer-invariant)
// emeta[p] = { j | bidx<<16,  f16x2 weights for dx=0 (dy0 lo, dy1 hi),  f16x2 for dx=1, 0 }
__global__ __launch_bounds__(256) void fill_kernel(const int* __restrict__ ei,
                                                   const int* __restrict__ ej,
                                                   const float* __restrict__ attr,
                                                   int* __restrict__ cursor,
                                                   uint4* __restrict__ emeta) {
    int e = blockIdx.x * 256 + threadIdx.x;
    if (e >= NE) return;
    int i = ei[e], j = ej[e];
    int p = atomicAdd(&cursor[i], 1);
    float2 a = ((const float2*)attr)[e];
    float d0 = fminf(fmaxf(a.x, -1.f), 1.f);
    float d1 = fminf(fmaxf(a.y, -1.f), 1.f);
    float tx = (d0 + 1.f) * 1.5f;
    float ty = (d1 + 1.f) * 1.5f;
    int ix = min(2, max(0, (int)floorf(tx)));
    int iy = min(2, max(0, (int)floorf(ty)));
    float ux = tx - (float)ix;
    float uy = ty - (float)iy;
    float m = (i != j) ? 1.f : 0.f;   // centerIgnore
    unsigned w0 = (unsigned)f2h((1.f - ux) * (1.f - uy) * m)      // dx0 dy0
                | ((unsigned)f2h((1.f - ux) * uy * m) << 16);     // dx0 dy1
    unsigned w1 = (unsigned)f2h(ux * (1.f - uy) * m)              // dx1 dy0
                | ((unsigned)f2h(ux * uy * m) << 16);             // dx1 dy1
    uint4 mm;
    mm.x = (unsigned)j | ((unsigned)(ix * 4 + iy) << 16);
    mm.y = w0;
    mm.z = w1;
    mm.w = 0;
    emeta[p] = mm;
}

// ---- y[n][544] = bf16( (relu?)A[n][0..31] @ Wext ), one MFMA per 16x16 tile (K=32)
__global__ __launch_bounds__(256) void gemm_kernel(const float* __restrict__ A,
                                                   const unsigned short* __restrict__ Wl,
                                                   unsigned short* __restrict__ y,
                                                   int relu) {
    int wv = threadIdx.x >> 6, lane = threadIdx.x & 63;
    int ct = blockIdx.y * 4 + wv;
    if (ct >= 34) return;                 // 544/16 = 34 col tiles
    int c0 = ct * 16;
    int m0 = blockIdx.x * 16;             // 20000/16 = 1250 exact
    int row = lane & 15;
    int kb = (lane >> 4) * 8;
    const float* ar = A + (size_t)(m0 + row) * 32 + kb;
    short8 av, bv;
#pragma unroll
    for (int i = 0; i < 8; i++) {
        float v = ar[i];
        if (relu) v = fmaxf(v, 0.f);
        av[i] = (short)f2bf(v);
    }
    int col = c0 + (lane & 15);
#pragma unroll
    for (int i = 0; i < 8; i++)
        bv[i] = (short)Wl[(size_t)(kb + i) * YS + col];
    f32x4 acc = {0.f, 0.f, 0.f, 0.f};
    acc = __builtin_amdgcn_mfma_f32_16x16x32_bf16(av, bv, acc, 0, 0, 0);
#pragma unroll
    for (int r = 0; r < 4; r++) {
        int orow = m0 + (lane >> 4) * 4 + r;   // C/D: col=lane&15, row=(lane>>4)*4+r
        y[(size_t)orow * YS + col] = f2bf(acc[r]);
    }
}

// ---- per-node accumulation: one wave per node, lane = (dx, dy, f-pair)
// Each lane gathers one dword (2 bf16) per edge; reduce over (dx,dy) via shfl_xor.
// mode: 0 = first layer, 1 = mid (residual), 2 = last (residual + scale -> d_out)
__global__ __launch_bounds__(256) void node_kernel(const unsigned short* __restrict__ y,
                                                   const uint4* __restrict__ emeta,
                                                   const int* __restrict__ rowst,
                                                   const float* __restrict__ bias,
                                                   const float* __restrict__ ansin,
                                                   float* __restrict__ ansout,
                                                   int mode) {
    int node = blockIdx.x * 4 + (threadIdx.x >> 6);
    int lane = threadIdx.x & 63;
    int fp = lane & 15;                 // feature pair: features 2fp, 2fp+1
    int dy = (lane >> 4) & 1;
    int dx = lane >> 5;
    int r0 = rowst[node], r1 = rowst[node + 1];
    int sub = (dx * 4 + dy) * 32 + fp * 2;   // element offset inside a y row (pre-bidx)
    float a0 = 0.f, a1 = 0.f;

    int q = r0;
    int qe = r0 + ((r1 - r0) & ~3);
    uint4 mb0, mb1, mb2, mb3;
    if (q < qe) {
        mb0 = emeta[q]; mb1 = emeta[q + 1]; mb2 = emeta[q + 2]; mb3 = emeta[q + 3];
    }
    for (; q < qe; q += 4) {
        uint4 m0 = mb0, m1 = mb1, m2 = mb2, m3 = mb3;
        if (q + 4 < qe) {   // prefetch next group
            mb0 = emeta[q + 4]; mb1 = emeta[q + 5]; mb2 = emeta[q + 6]; mb3 = emeta[q + 7];
        }
        unsigned v0 = *(const unsigned*)(y + (m0.x & 0xFFFF) * YS + (m0.x >> 16) * 32 + sub);
        unsigned v1 = *(const unsigned*)(y + (m1.x & 0xFFFF) * YS + (m1.x >> 16) * 32 + sub);
        unsigned v2 = *(const unsigned*)(y + (m2.x & 0xFFFF) * YS + (m2.x >> 16) * 32 + sub);
        unsigned v3 = *(const unsigned*)(y + (m3.x & 0xFFFF) * YS + (m3.x >> 16) * 32 + sub);
        unsigned wb;
        float w;
        wb = dx ? m0.z : m0.y; w = h2f((unsigned short)(dy ? (wb >> 16) : (wb & 0xFFFF)));
        a0 += w * bf2f((unsigned short)(v0 & 0xFFFF));
        a1 += w * bf2f((unsigned short)(v0 >> 16));
        wb = dx ? m1.z : m1.y; w = h2f((unsigned short)(dy ? (wb >> 16) : (wb & 0xFFFF)));
        a0 += w * bf2f((unsigned short)(v1 & 0xFFFF));
        a1 += w * bf2f((unsigned short)(v1 >> 16));
        wb = dx ? m2.z : m2.y; w = h2f((unsigned short)(dy ? (wb >> 16) : (wb & 0xFFFF)));
        a0 += w * bf2f((unsigned short)(v2 & 0xFFFF));
        a1 += w * bf2f((unsigned short)(v2 >> 16));
        wb = dx ? m3.z : m3.y; w = h2f((unsigned short)(dy ? (wb >> 16) : (wb & 0xFFFF)));
        a0 += w * bf2f((unsigned short)(v3 & 0xFFFF));
        a1 += w * bf2f((unsigned short)(v3 >> 16));
    }
    for (; q < r1; ++q) {
        uint4 mm = emeta[q];
        unsigned v = *(const unsigned*)(y + (mm.x & 0xFFFF) * YS + (mm.x >> 16) * 32 + sub);
        unsigned wb = dx ? mm.z : mm.y;
        float w = h2f((unsigned short)(dy ? (wb >> 16) : (wb & 0xFFFF)));
        a0 += w * bf2f((unsigned short)(v & 0xFFFF));
        a1 += w * bf2f((unsigned short)(v >> 16));
    }

    a0 += __shfl_xor(a0, 32); a1 += __shfl_xor(a1, 32);   // sum over dx
    a0 += __shfl_xor(a0, 16); a1 += __shfl_xor(a1, 16);   // sum over dy
    if (lane < 16) {
        int f0 = fp * 2;
        unsigned fcb = *(const unsigned*)(y + (size_t)node * YS + 512 + f0);
        float2 bs = ((const float2*)bias)[fp];
        float o0 = a0 + bf2f((unsigned short)(fcb & 0xFFFF)) + bs.x;
        float o1 = a1 + bf2f((unsigned short)(fcb >> 16)) + bs.y;
        if (mode) {
            float2 r = ((const float2*)ansin)[(size_t)node * 16 + fp];
            o0 += r.x; o1 += r.y;
        }
        if (mode == 2) { o0 *= (1.f / 128.f); o1 *= (1.f / 128.f); }
        float2 o; o.x = o0; o.y = o1;
        ((float2*)ansout)[(size_t)node * 16 + fp] = o;
    }
}

extern "C" void kernel_launch(void* const* d_in, const int* in_sizes, int n_in,
                              void* d_out, int out_size, void* d_ws, size_t ws_size,
                              hipStream_t stream) {
    const float* feat = (const float*)d_in[0];
    const int* ei = (const int*)d_in[1];
    const int* ej = (const int*)d_in[2];
    const float* attr = (const float*)d_in[3];
    WPtrs wp;
    const float* fcB[4];
    if (n_in >= 16) {
        for (int l = 0; l < 4; l++) {
            wp.cw[l] = (const float*)d_in[4 + l];
            wp.fw[l] = (const float*)d_in[8 + l];
            fcB[l]   = (const float*)d_in[12 + l];
        }
    } else {
        const float* cb = (const float*)d_in[4];
        const float* fb = (const float*)d_in[5];
        const float* bb = (const float*)d_in[6];
        for (int l = 0; l < 4; l++) {
            wp.cw[l] = cb + (size_t)l * 16 * 32 * 32;
            wp.fw[l] = fb + (size_t)l * 32 * 32;
            fcB[l]   = bb + (size_t)l * 32;
        }
    }

    // workspace bump allocator (256B aligned)
    char* p = (char*)d_ws;
    auto alloc = [&](size_t bytes) -> void* {
        void* r = (void*)p;
        p += (bytes + 255) & ~(size_t)255;
        return r;
    };
    unsigned short* wext = (unsigned short*)alloc(4 * 32 * YS * sizeof(unsigned short));
    uint4* emeta  = (uint4*)alloc((size_t)NE * sizeof(uint4));
    int* counts   = (int*)alloc((size_t)NN * sizeof(int));
    int* cursor   = (int*)alloc((size_t)NN * sizeof(int));
    int* rowst    = (int*)alloc((size_t)(NN + 1) * sizeof(int));
    unsigned short* y = (unsigned short*)alloc((size_t)NN * YS * sizeof(unsigned short));
    float* ans    = (float*)alloc((size_t)NN * FDIM * sizeof(float));
    float* outf   = (float*)d_out;

    hipMemsetAsync(counts, 0, (size_t)NN * sizeof(int), stream);

    prepw_kernel<<<(4 * 32 * YS + 255) / 256, 256, 0, stream>>>(wp, wext);
    hist_kernel<<<(NE + 255) / 256, 256, 0, stream>>>(ei, counts);
    scan_kernel<<<1, 1024, 0, stream>>>(counts, rowst, cursor);
    fill_kernel<<<(NE + 255) / 256, 256, 0, stream>>>(ei, ej, attr, cursor, emeta);

    for (int l = 0; l < 4; l++) {
        const float* A = (l == 0) ? feat : ans;
        gemm_kernel<<<dim3(NN / 16, 9), 256, 0, stream>>>(A, wext + (size_t)l * 32 * YS, y, l > 0);
        int mode = (l == 0) ? 0 : ((l == 3) ? 2 : 1);
        float* dst = (l == 3) ? outf : ans;
        node_kernel<<<NN / 4, 256, 0, stream>>>(y, emeta, rowst, fcB[l],
                                                ans, dst, mode);
    }
}

// Round 4
// 222.935 us; speedup vs baseline: 1.3774x; 1.0172x over previous
//
#include <hip/hip_runtime.h>
#include <hip/hip_bf16.h>

#define NN 20000
#define NE 320000
#define FDIM 32
#define YS 544      // 16 conv basis blocks * 32 + 32 fc cols

typedef __attribute__((ext_vector_type(8))) short short8;
typedef __attribute__((ext_vector_type(4))) float f32x4;

__device__ __forceinline__ unsigned short f2bf(float v) {
    unsigned u = __float_as_uint(v);
    unsigned r = (u + 0x7fffu + ((u >> 16) & 1u)) >> 16;
    return (unsigned short)r;
}
__device__ __forceinline__ float bf2f(unsigned short s) {
    return __uint_as_float(((unsigned)s) << 16);
}
__device__ __forceinline__ unsigned short f2h(float v) {
    union { _Float16 h; unsigned short u; } cv;
    cv.h = (_Float16)v;
    return cv.u;
}
__device__ __forceinline__ float h2f(unsigned short u) {
    union { unsigned short u; _Float16 h; } cv;
    cv.u = u;
    return (float)cv.h;
}

struct WPtrs { const float* cw[4]; const float* fw[4]; };

// ---- fused: blocks [0,1250) histogram edges; blocks [1250, 1250+272) build Wext
__global__ __launch_bounds__(256) void histprep_kernel(const int* __restrict__ ei,
                                                       int* __restrict__ counts,
                                                       WPtrs wp,
                                                       unsigned short* __restrict__ out) {
    int b = blockIdx.x;
    if (b < (NE + 255) / 256) {
        int e = b * 256 + threadIdx.x;
        if (e < NE) atomicAdd(&counts[ei[e]], 1);
    } else {
        int idx = (b - (NE + 255) / 256) * 256 + threadIdx.x;   // 4 * 32*544 = 69632
        if (idx >= 4 * 32 * YS) return;
        int l = idx / (32 * YS);
        int r = idx - l * 32 * YS;
        int k = r / YS, c = r - k * YS;
        float v = (c < 512) ? wp.cw[l][((c >> 5) * 32 + k) * 32 + (c & 31)]
                            : wp.fw[l][k * 32 + (c & 31)];
        out[idx] = f2bf(v);
    }
}

// ---- CSR build: single-block scan, 20 elements/thread, fully unrolled
__global__ __launch_bounds__(1024) void scan_kernel(const int* __restrict__ counts,
                                                    int* __restrict__ rowst,
                                                    int* __restrict__ cursor) {
    __shared__ int s[1024];
    int t = threadIdx.x;
    int base = t * 20;                    // 1024*20 = 20480 >= 20000
    int v[20];
    int sum = 0;
#pragma unroll
    for (int i = 0; i < 20; i++) {
        int idx = base + i;
        v[i] = (idx < NN) ? counts[idx] : 0;
        sum += v[i];
    }
    s[t] = sum;
    __syncthreads();
#pragma unroll
    for (int off = 1; off < 1024; off <<= 1) {
        int add = (t >= off) ? s[t - off] : 0;
        __syncthreads();
        s[t] += add;
        __syncthreads();
    }
    int run = s[t] - sum;                 // exclusive across threads
    if (t == 0) rowst[0] = 0;
#pragma unroll
    for (int i = 0; i < 20; i++) {
        int idx = base + i;
        if (idx < NN) {
            cursor[idx] = run;
            rowst[idx + 1] = run + v[i];
        }
        run += v[i];
    }
}

// ---- CSR fill + edge basis precompute (phi is layer-invariant)
// emeta[p] = { j | bidx<<16,  f16x2 weights for dx=0 (dy0 lo, dy1 hi),  f16x2 for dx=1, 0 }
__global__ __launch_bounds__(256) void fill_kernel(const int* __restrict__ ei,
                                                   const int* __restrict__ ej,
                                                   const float* __restrict__ attr,
                                                   int* __restrict__ cursor,
                                                   uint4* __restrict__ emeta) {
    int e = blockIdx.x * 256 + threadIdx.x;
    if (e >= NE) return;
    int i = ei[e], j = ej[e];
    int p = atomicAdd(&cursor[i], 1);
    float2 a = ((const float2*)attr)[e];
    float d0 = fminf(fmaxf(a.x, -1.f), 1.f);
    float d1 = fminf(fmaxf(a.y, -1.f), 1.f);
    float tx = (d0 + 1.f) * 1.5f;
    float ty = (d1 + 1.f) * 1.5f;
    int ix = min(2, max(0, (int)floorf(tx)));
    int iy = min(2, max(0, (int)floorf(ty)));
    float ux = tx - (float)ix;
    float uy = ty - (float)iy;
    float m = (i != j) ? 1.f : 0.f;   // centerIgnore
    unsigned w0 = (unsigned)f2h((1.f - ux) * (1.f - uy) * m)      // dx0 dy0
                | ((unsigned)f2h((1.f - ux) * uy * m) << 16);     // dx0 dy1
    unsigned w1 = (unsigned)f2h(ux * (1.f - uy) * m)              // dx1 dy0
                | ((unsigned)f2h(ux * uy * m) << 16);             // dx1 dy1
    uint4 mm;
    mm.x = (unsigned)j | ((unsigned)(ix * 4 + iy) << 16);
    mm.y = w0;
    mm.z = w1;
    mm.w = 0;
    emeta[p] = mm;
}

// ---- y[n][544] = bf16( (relu?)A[n][0..31] @ Wext )
// 1250 blocks; each wave holds its A-fragment and loops over col-tiles.
__global__ __launch_bounds__(256) void gemm_kernel(const float* __restrict__ A,
                                                   const unsigned short* __restrict__ Wl,
                                                   unsigned short* __restrict__ y,
                                                   int relu) {
    int wv = threadIdx.x >> 6, lane = threadIdx.x & 63;
    int m0 = blockIdx.x * 16;             // 20000/16 = 1250 exact
    int row = lane & 15;
    int kb = (lane >> 4) * 8;
    const float* ar = A + (size_t)(m0 + row) * 32 + kb;
    short8 av;
#pragma unroll
    for (int i = 0; i < 8; i++) {
        float v = ar[i];
        if (relu) v = fmaxf(v, 0.f);
        av[i] = (short)f2bf(v);
    }
    int orow0 = m0 + (lane >> 4) * 4;     // C/D: col=lane&15, row=(lane>>4)*4+r
    for (int ct = wv; ct < 34; ct += 4) {
        int col = ct * 16 + row;
        short8 bv;
#pragma unroll
        for (int i = 0; i < 8; i++)
            bv[i] = (short)Wl[(size_t)(kb + i) * YS + col];
        f32x4 acc = {0.f, 0.f, 0.f, 0.f};
        acc = __builtin_amdgcn_mfma_f32_16x16x32_bf16(av, bv, acc, 0, 0, 0);
#pragma unroll
        for (int r = 0; r < 4; r++)
            y[(size_t)(orow0 + r) * YS + col] = f2bf(acc[r]);
    }
}

// ---- per-node accumulation: one wave per node, lane = (dx, dy, f-pair)
// Groups of 8 edges, clamped indices + zeroed weights for the tail -> 8 gathers
// always in flight, no serial tail.
// mode: 0 = first layer, 1 = mid (residual), 2 = last (residual + scale -> d_out)
__global__ __launch_bounds__(256) void node_kernel(const unsigned short* __restrict__ y,
                                                   const uint4* __restrict__ emeta,
                                                   const int* __restrict__ rowst,
                                                   const float* __restrict__ bias,
                                                   const float* __restrict__ ansin,
                                                   float* __restrict__ ansout,
                                                   int mode) {
    int node = blockIdx.x * 4 + (threadIdx.x >> 6);
    int lane = threadIdx.x & 63;
    int fp = lane & 15;                 // feature pair: features 2fp, 2fp+1
    int dy = (lane >> 4) & 1;
    int dx = lane >> 5;
    int r0 = rowst[node], r1 = rowst[node + 1];
    int sub = (dx * 4 + dy) * 32 + fp * 2;   // element offset inside a y row (pre-bidx)
    float a0 = 0.f, a1 = 0.f;

    if (r1 > r0) {
        int last = r1 - 1;
        uint4 mb[8];
#pragma unroll
        for (int k = 0; k < 8; k++) mb[k] = emeta[min(r0 + k, last)];
        for (int q = r0; q < r1; q += 8) {
            uint4 mc[8];
#pragma unroll
            for (int k = 0; k < 8; k++) mc[k] = mb[k];
            if (q + 8 < r1) {
#pragma unroll
                for (int k = 0; k < 8; k++) mb[k] = emeta[min(q + 8 + k, last)];
            }
            unsigned vv[8];
#pragma unroll
            for (int k = 0; k < 8; k++)
                vv[k] = *(const unsigned*)(y + (size_t)(mc[k].x & 0xFFFF) * YS
                                             + (mc[k].x >> 16) * 32 + sub);
#pragma unroll
            for (int k = 0; k < 8; k++) {
                unsigned wb = dx ? mc[k].z : mc[k].y;
                float w = h2f((unsigned short)(dy ? (wb >> 16) : (wb & 0xFFFF)));
                w = (q + k < r1) ? w : 0.f;
                a0 += w * bf2f((unsigned short)(vv[k] & 0xFFFF));
                a1 += w * bf2f((unsigned short)(vv[k] >> 16));
            }
        }
    }

    a0 += __shfl_xor(a0, 32); a1 += __shfl_xor(a1, 32);   // sum over dx
    a0 += __shfl_xor(a0, 16); a1 += __shfl_xor(a1, 16);   // sum over dy
    if (lane < 16) {
        int f0 = fp * 2;
        unsigned fcb = *(const unsigned*)(y + (size_t)node * YS + 512 + f0);
        float2 bs = ((const float2*)bias)[fp];
        float o0 = a0 + bf2f((unsigned short)(fcb & 0xFFFF)) + bs.x;
        float o1 = a1 + bf2f((unsigned short)(fcb >> 16)) + bs.y;
        if (mode) {
            float2 r = ((const float2*)ansin)[(size_t)node * 16 + fp];
            o0 += r.x; o1 += r.y;
        }
        if (mode == 2) { o0 *= (1.f / 128.f); o1 *= (1.f / 128.f); }
        float2 o; o.x = o0; o.y = o1;
        ((float2*)ansout)[(size_t)node * 16 + fp] = o;
    }
}

extern "C" void kernel_launch(void* const* d_in, const int* in_sizes, int n_in,
                              void* d_out, int out_size, void* d_ws, size_t ws_size,
                              hipStream_t stream) {
    const float* feat = (const float*)d_in[0];
    const int* ei = (const int*)d_in[1];
    const int* ej = (const int*)d_in[2];
    const float* attr = (const float*)d_in[3];
    WPtrs wp;
    const float* fcB[4];
    if (n_in >= 16) {
        for (int l = 0; l < 4; l++) {
            wp.cw[l] = (const float*)d_in[4 + l];
            wp.fw[l] = (const float*)d_in[8 + l];
            fcB[l]   = (const float*)d_in[12 + l];
        }
    } else {
        const float* cb = (const float*)d_in[4];
        const float* fb = (const float*)d_in[5];
        const float* bb = (const float*)d_in[6];
        for (int l = 0; l < 4; l++) {
            wp.cw[l] = cb + (size_t)l * 16 * 32 * 32;
            wp.fw[l] = fb + (size_t)l * 32 * 32;
            fcB[l]   = bb + (size_t)l * 32;
        }
    }

    // workspace bump allocator (256B aligned)
    char* p = (char*)d_ws;
    auto alloc = [&](size_t bytes) -> void* {
        void* r = (void*)p;
        p += (bytes + 255) & ~(size_t)255;
        return r;
    };
    unsigned short* wext = (unsigned short*)alloc(4 * 32 * YS * sizeof(unsigned short));
    uint4* emeta  = (uint4*)alloc((size_t)NE * sizeof(uint4));
    int* counts   = (int*)alloc((size_t)NN * sizeof(int));
    int* cursor   = (int*)alloc((size_t)NN * sizeof(int));
    int* rowst    = (int*)alloc((size_t)(NN + 1) * sizeof(int));
    unsigned short* y = (unsigned short*)alloc((size_t)NN * YS * sizeof(unsigned short));
    float* ans    = (float*)alloc((size_t)NN * FDIM * sizeof(float));
    float* outf   = (float*)d_out;

    hipMemsetAsync(counts, 0, (size_t)NN * sizeof(int), stream);

    int histBlocks = (NE + 255) / 256;
    int prepBlocks = (4 * 32 * YS + 255) / 256;
    histprep_kernel<<<histBlocks + prepBlocks, 256, 0, stream>>>(ei, counts, wp, wext);
    scan_kernel<<<1, 1024, 0, stream>>>(counts, rowst, cursor);
    fill_kernel<<<(NE + 255) / 256, 256, 0, stream>>>(ei, ej, attr, cursor, emeta);

    for (int l = 0; l < 4; l++) {
        const float* A = (l == 0) ? feat : ans;
        gemm_kernel<<<NN / 16, 256, 0, stream>>>(A, wext + (size_t)l * 32 * YS, y, l > 0);
        int mode = (l == 0) ? 0 : ((l == 3) ? 2 : 1);
        float* dst = (l == 3) ? outf : ans;
        node_kernel<<<NN / 4, 256, 0, stream>>>(y, emeta, rowst, fcB[l],
                                                ans, dst, mode);
    }
}